// Round 2
// baseline (475.010 us; speedup 1.0000x reference)
//
#include <hip/hip_runtime.h>
#include <hip/hip_bf16.h>

typedef __attribute__((ext_vector_type(8))) short bf16x8;
typedef __attribute__((ext_vector_type(4))) float f32x4;

#define SEQ 2048
#define NB 4
#define NH 16
#define HID 1024

__device__ __forceinline__ short f2bf(float f) {
  __hip_bfloat16 h = __float2bfloat16(f);
  union { __hip_bfloat16 h; short s; } u; u.h = h; return u.s;
}

__device__ __forceinline__ void gload_lds16(const void* g, void* l) {
  __builtin_amdgcn_global_load_lds((const __attribute__((address_space(1))) void*)g,
                                   (__attribute__((address_space(3))) void*)l, 16, 0, 0);
}

__global__ void cvt_f32_bf16(const float4* __restrict__ in, short4* __restrict__ out, int n4) {
  int i = blockIdx.x * 256 + threadIdx.x;
  if (i >= n4) return;
  float4 v = in[i];
  short4 o;
  o.x = f2bf(v.x); o.y = f2bf(v.y); o.z = f2bf(v.z); o.w = f2bf(v.w);
  out[i] = o;
}

// C = A @ B^T (+bias). A: [M,1024] bf16 row-major. B: [N,1024] bf16 row-major (torch Linear weight).
// MODE 0: fused QKV (N=3072 over three weight mats), writes bf16 [B,H,S,D], Q scaled by 0.125.
// MODE 1: O-proj, writes fp32 [M,1024] + bias.
template<int MODE>
__global__ __launch_bounds__(256, 2)
void gemm_bf16(const short* __restrict__ A,
               const short* __restrict__ B0, const short* __restrict__ B1, const short* __restrict__ B2,
               const float* __restrict__ bias0, const float* __restrict__ bias1, const float* __restrict__ bias2,
               short* __restrict__ o0, short* __restrict__ o1, short* __restrict__ o2,
               float* __restrict__ of) {
  __shared__ __align__(16) short As[128*64];
  __shared__ __align__(16) short Bs[128*64];
  const int tid = threadIdx.x;
  const int wave = tid >> 6, lane = tid & 63;
  const int lr = lane & 15, lk = lane >> 4;
  const int m0 = blockIdx.y * 128;
  const int n0 = blockIdx.x * 128;

  const short* Bm; const float* bias; int nloc; int proj = 0;
  if (MODE == 0) {
    proj = n0 >> 10;
    Bm   = proj == 0 ? B0 : (proj == 1 ? B1 : B2);
    bias = proj == 0 ? bias0 : (proj == 1 ? bias1 : bias2);
    nloc = n0 & 1023;
  } else { Bm = B0; bias = bias0; nloc = n0; }

  f32x4 acc[4][4];
  #pragma unroll
  for (int m = 0; m < 4; ++m)
    #pragma unroll
    for (int n = 0; n < 4; ++n) acc[m][n] = (f32x4){0.f,0.f,0.f,0.f};

  const int wr = (wave >> 1) * 64, wc = (wave & 1) * 64;

  for (int kt = 0; kt < 1024; kt += 64) {
    // Stage A,B tiles [128][64] via global_load_lds, pre-swizzled source so that
    // read-side XOR ( slot ^ (row&7) ) lands on the right data (rule #21).
    #pragma unroll
    for (int is = 0; is < 4; ++is) {
      int slot = is*256 + tid;
      int r = slot >> 3;
      int cs = (slot & 7) ^ (r & 7);
      gload_lds16(A  + (m0  + r)*1024 + kt + cs*8, As + (is*256 + wave*64)*8);
      gload_lds16(Bm + (nloc+ r)*1024 + kt + cs*8, Bs + (is*256 + wave*64)*8);
    }
    __syncthreads();
    #pragma unroll
    for (int kk = 0; kk < 2; ++kk) {
      bf16x8 av[4], bv[4];
      #pragma unroll
      for (int m = 0; m < 4; ++m) {
        int r = wr + m*16 + lr;
        av[m] = *(const bf16x8*)(As + (r*8 + ((kk*4 + lk) ^ (r & 7)))*8);
      }
      #pragma unroll
      for (int n = 0; n < 4; ++n) {
        int r = wc + n*16 + lr;
        bv[n] = *(const bf16x8*)(Bs + (r*8 + ((kk*4 + lk) ^ (r & 7)))*8);
      }
      #pragma unroll
      for (int m = 0; m < 4; ++m)
        #pragma unroll
        for (int n = 0; n < 4; ++n)
          acc[m][n] = __builtin_amdgcn_mfma_f32_16x16x32_bf16(av[m], bv[n], acc[m][n], 0, 0, 0);
    }
    __syncthreads();
  }

  // Epilogue. C/D frag layout: col = lane&15, row = (lane>>4)*4 + j  [m89].
  if (MODE == 0) {
    short* outp = proj == 0 ? o0 : (proj == 1 ? o1 : o2);
    const float scale = (proj == 0) ? 0.125f : 1.0f;  // fold 1/sqrt(64) into Q
    #pragma unroll
    for (int n = 0; n < 4; ++n) {
      int col = nloc + wc + n*16 + lr;   // 0..1023 within projection
      int h = col >> 6, d = col & 63;
      float bvv = bias[col];
      #pragma unroll
      for (int m = 0; m < 4; ++m)
        #pragma unroll
        for (int j = 0; j < 4; ++j) {
          int row = m0 + wr + m*16 + lk*4 + j;  // b*2048 + s
          int b = row >> 11, s = row & 2047;
          outp[(((b*NH + h)*SEQ + s) << 6) + d] = f2bf((acc[m][n][j] + bvv) * scale);
        }
    }
  } else {
    #pragma unroll
    for (int n = 0; n < 4; ++n) {
      int col = n0 + wc + n*16 + lr;
      float bvv = bias[col];
      #pragma unroll
      for (int m = 0; m < 4; ++m)
        #pragma unroll
        for (int j = 0; j < 4; ++j) {
          int row = m0 + wr + m*16 + lk*4 + j;
          of[row*HID + col] = acc[m][n][j] + bvv;
        }
    }
  }
}

// Flash attention. Q,K,V: [B,H,S,64] bf16 (Q pre-scaled by 0.125). O: [B,S,H*64] bf16.
// Block = (b,h, 64 q-rows); wave w owns q-rows [q0+w*16, +16). KV tiles of 64.
__global__ __launch_bounds__(256, 2)
void attn_fwd(const short* __restrict__ Q, const short* __restrict__ K,
              const short* __restrict__ V, const float* __restrict__ head_mask,
              short* __restrict__ O) {
  __shared__ __align__(16) short Ks[64*64];      // [kv][d], swizzled
  __shared__ __align__(16) short Vt[64*64];      // [d][kv], swizzled
  __shared__ __align__(16) short Ps[4][16*64];   // per-wave P, [q][kv], swizzled
  const int tid = threadIdx.x;
  const int wave = tid >> 6, lane = tid & 63;
  const int lr = lane & 15, lk = lane >> 4;
  const int bh = blockIdx.y;
  const int h = bh & (NH - 1);
  const int q0 = blockIdx.x * 64;
  const int base = bh * SEQ * 64;
  const short* Qh = Q + base;
  const short* Kh = K + base;
  const short* Vh = V + base;

  // Hoist Q fragments: A-operand rows = lane&15, k = (lane>>4)*8 + j
  bf16x8 qf[2];
  {
    const short* qr = Qh + (q0 + wave*16 + lr)*64 + lk*8;
    qf[0] = *(const bf16x8*)qr;
    qf[1] = *(const bf16x8*)(qr + 32);
  }

  float row_m[4], row_l[4];
  f32x4 oacc[4];
  #pragma unroll
  for (int j = 0; j < 4; ++j) { row_m[j] = -1e30f; row_l[j] = 0.f; }
  #pragma unroll
  for (int n = 0; n < 4; ++n) oacc[n] = (f32x4){0.f,0.f,0.f,0.f};

  for (int kv0 = 0; kv0 < SEQ; kv0 += 64) {
    // Stage K [64][64] (pre-swizzled source, linear LDS dest)
    #pragma unroll
    for (int is = 0; is < 2; ++is) {
      int slot = is*256 + tid;
      int r = slot >> 3;
      int cs = (slot & 7) ^ (r & 7);
      gload_lds16(Kh + (kv0 + r)*64 + cs*8, Ks + (is*256 + wave*64)*8);
    }
    // Stage V transposed -> Vt[d][kv] (reg round-trip, swizzled scalar writes)
    #pragma unroll
    for (int is = 0; is < 2; ++is) {
      int r = is*32 + (tid >> 3);   // kv row
      int c8 = tid & 7;             // d-slot
      bf16x8 v = *(const bf16x8*)(Vh + (kv0 + r)*64 + c8*8);
      #pragma unroll
      for (int j = 0; j < 8; ++j) {
        int d = c8*8 + j;
        int byteoff = d*128 + (((r >> 3) ^ (d & 7))*16) + (r & 7)*2;
        *(short*)((char*)Vt + byteoff) = v[j];
      }
    }
    __syncthreads();

    // S = Q @ K^T : frag n covers kv cols [n*16, n*16+16)
    f32x4 sc[4];
    #pragma unroll
    for (int n = 0; n < 4; ++n) sc[n] = (f32x4){0.f,0.f,0.f,0.f};
    #pragma unroll
    for (int kk = 0; kk < 2; ++kk)
      #pragma unroll
      for (int n = 0; n < 4; ++n) {
        int r = n*16 + lr;
        bf16x8 bv = *(const bf16x8*)(Ks + (r*8 + ((kk*4 + lk) ^ (r & 7)))*8);
        sc[n] = __builtin_amdgcn_mfma_f32_16x16x32_bf16(qf[kk], bv, sc[n], 0, 0, 0);
      }

    // Online softmax. q-row = lk*4+j lives in lanes [lk*16, lk*16+16), reg j.
    float pmax[4];
    #pragma unroll
    for (int j = 0; j < 4; ++j) {
      float v = fmaxf(fmaxf(sc[0][j], sc[1][j]), fmaxf(sc[2][j], sc[3][j]));
      v = fmaxf(v, __shfl_xor(v, 1));
      v = fmaxf(v, __shfl_xor(v, 2));
      v = fmaxf(v, __shfl_xor(v, 4));
      v = fmaxf(v, __shfl_xor(v, 8));
      pmax[j] = v;
    }
    float ps[4], rs[4];
    #pragma unroll
    for (int j = 0; j < 4; ++j) {
      float mn = fmaxf(row_m[j], pmax[j]);
      ps[j] = __expf(row_m[j] - mn);
      row_m[j] = mn;
      rs[j] = 0.f;
    }
    #pragma unroll
    for (int n = 0; n < 4; ++n)
      #pragma unroll
      for (int j = 0; j < 4; ++j) {
        float p = __expf(sc[n][j] - row_m[j]);
        sc[n][j] = p;
        rs[j] += p;
      }
    #pragma unroll
    for (int j = 0; j < 4; ++j) {
      float v = rs[j];
      v += __shfl_xor(v, 1);
      v += __shfl_xor(v, 2);
      v += __shfl_xor(v, 4);
      v += __shfl_xor(v, 8);
      row_l[j] = row_l[j]*ps[j] + v;
    }
    #pragma unroll
    for (int n = 0; n < 4; ++n)
      #pragma unroll
      for (int j = 0; j < 4; ++j) oacc[n][j] *= ps[j];

    // P -> per-wave LDS (bf16, swizzled) to become PV's A-operand
    short* Pw = Ps[wave];
    #pragma unroll
    for (int n = 0; n < 4; ++n)
      #pragma unroll
      for (int j = 0; j < 4; ++j) {
        int row = lk*4 + j;
        int col = n*16 + lr;
        int byteoff = row*128 + (((col >> 3) ^ (row & 7))*16) + (col & 7)*2;
        *(short*)((char*)Pw + byteoff) = f2bf(sc[n][j]);
      }
    __syncthreads();

    // O += P @ V ; frag n covers d cols [n*16, n*16+16)
    #pragma unroll
    for (int kk = 0; kk < 2; ++kk) {
      bf16x8 av = *(const bf16x8*)(Pw + (lr*8 + ((kk*4 + lk) ^ (lr & 7)))*8);
      #pragma unroll
      for (int n = 0; n < 4; ++n) {
        int r = n*16 + lr;
        bf16x8 bv = *(const bf16x8*)(Vt + (r*8 + ((kk*4 + lk) ^ (r & 7)))*8);
        oacc[n] = __builtin_amdgcn_mfma_f32_16x16x32_bf16(av, bv, oacc[n], 0, 0, 0);
      }
    }
    __syncthreads();
  }

  const float hm = head_mask[h];
  const int b = bh >> 4;
  #pragma unroll
  for (int j = 0; j < 4; ++j) {
    int q = q0 + wave*16 + lk*4 + j;
    float inv = hm / row_l[j];
    int rowbase = (b*SEQ + q)*HID + h*64;
    #pragma unroll
    for (int n = 0; n < 4; ++n)
      O[rowbase + n*16 + lr] = f2bf(oacc[n][j] * inv);
  }
}

extern "C" void kernel_launch(void* const* d_in, const int* in_sizes, int n_in,
                              void* d_out, int out_size, void* d_ws, size_t ws_size,
                              hipStream_t stream) {
  const float* x  = (const float*)d_in[0];
  const float* Wq = (const float*)d_in[1];
  const float* bq = (const float*)d_in[2];
  const float* Wk = (const float*)d_in[3];
  const float* bk = (const float*)d_in[4];
  const float* Wv = (const float*)d_in[5];
  const float* bv = (const float*)d_in[6];
  const float* Wo = (const float*)d_in[7];
  const float* bo = (const float*)d_in[8];
  const float* hm = (const float*)d_in[9];
  float* out = (float*)d_out;
  char* ws = (char*)d_ws;

  // ws layout (bytes): xb 16MB | 4x W 2MB | Q 16MB | K 16MB | V 16MB | attnO 16MB
  short* xb  = (short*)(ws);
  short* wqb = (short*)(ws + 16777216);
  short* wkb = (short*)(ws + 18874368);
  short* wvb = (short*)(ws + 20971520);
  short* wob = (short*)(ws + 23068672);
  short* Qb  = (short*)(ws + 25165824);
  short* Kb  = (short*)(ws + 41943040);
  short* Vb  = (short*)(ws + 58720256);
  short* AOb = (short*)(ws + 75497472);

  cvt_f32_bf16<<<8192, 256, 0, stream>>>((const float4*)x,  (short4*)xb,  2097152);
  cvt_f32_bf16<<<1024, 256, 0, stream>>>((const float4*)Wq, (short4*)wqb, 262144);
  cvt_f32_bf16<<<1024, 256, 0, stream>>>((const float4*)Wk, (short4*)wkb, 262144);
  cvt_f32_bf16<<<1024, 256, 0, stream>>>((const float4*)Wv, (short4*)wvb, 262144);
  cvt_f32_bf16<<<1024, 256, 0, stream>>>((const float4*)Wo, (short4*)wob, 262144);

  // Fused QKV: M=8192, N=3072, K=1024
  gemm_bf16<0><<<dim3(24, 64), 256, 0, stream>>>(xb, wqb, wkb, wvb, bq, bk, bv,
                                                 Qb, Kb, Vb, nullptr);
  // Attention: grid (S/64, B*H)
  attn_fwd<<<dim3(32, 64), 256, 0, stream>>>(Qb, Kb, Vb, hm, AOb);
  // O-proj: M=8192, N=1024
  gemm_bf16<1><<<dim3(8, 64), 256, 0, stream>>>(AOb, wob, nullptr, nullptr, bo, nullptr, nullptr,
                                                nullptr, nullptr, nullptr, out);
}

// Round 3
// 392.480 us; speedup vs baseline: 1.2103x; 1.2103x over previous
//
#include <hip/hip_runtime.h>
#include <hip/hip_bf16.h>

typedef __attribute__((ext_vector_type(8))) short bf16x8;
typedef __attribute__((ext_vector_type(4))) float f32x4;

#define SEQ 2048
#define NB 4
#define NH 16
#define HID 1024

__device__ __forceinline__ short f2bf(float f) {
  __hip_bfloat16 h = __float2bfloat16(f);
  union { __hip_bfloat16 h; short s; } u; u.h = h; return u.s;
}

__device__ __forceinline__ void gload_lds16(const void* g, void* l) {
  __builtin_amdgcn_global_load_lds((const __attribute__((address_space(1))) void*)g,
                                   (__attribute__((address_space(3))) void*)l, 16, 0, 0);
}

__global__ void cvt_f32_bf16(const float4* __restrict__ in, short4* __restrict__ out, int n4) {
  int i = blockIdx.x * 256 + threadIdx.x;
  if (i >= n4) return;
  float4 v = in[i];
  short4 o;
  o.x = f2bf(v.x); o.y = f2bf(v.y); o.z = f2bf(v.z); o.w = f2bf(v.w);
  out[i] = o;
}

// C = A @ B^T (+bias). A: [M,1024] bf16 row-major. B: [N,1024] bf16 row-major.
// MODE 0: fused QKV. Q,K -> bf16 [B,H,S,64] (Q scaled 0.125). V -> bf16 [B,H,64,S] (transposed!).
// MODE 1: O-proj, writes fp32 [M,1024] + bias.
template<int MODE>
__global__ __launch_bounds__(256, 2)
void gemm_bf16(const short* __restrict__ A,
               const short* __restrict__ B0, const short* __restrict__ B1, const short* __restrict__ B2,
               const float* __restrict__ bias0, const float* __restrict__ bias1, const float* __restrict__ bias2,
               short* __restrict__ o0, short* __restrict__ o1, short* __restrict__ o2,
               float* __restrict__ of) {
  __shared__ __align__(16) short As[128*64];
  __shared__ __align__(16) short Bs[128*64];
  const int tid = threadIdx.x;
  const int wave = tid >> 6, lane = tid & 63;
  const int lr = lane & 15, lk = lane >> 4;
  const int m0 = blockIdx.y * 128;
  const int n0 = blockIdx.x * 128;

  const short* Bm; const float* bias; int nloc; int proj = 0;
  if (MODE == 0) {
    proj = n0 >> 10;
    Bm   = proj == 0 ? B0 : (proj == 1 ? B1 : B2);
    bias = proj == 0 ? bias0 : (proj == 1 ? bias1 : bias2);
    nloc = n0 & 1023;
  } else { Bm = B0; bias = bias0; nloc = n0; }

  f32x4 acc[4][4];
  #pragma unroll
  for (int m = 0; m < 4; ++m)
    #pragma unroll
    for (int n = 0; n < 4; ++n) acc[m][n] = (f32x4){0.f,0.f,0.f,0.f};

  const int wr = (wave >> 1) * 64, wc = (wave & 1) * 64;

  for (int kt = 0; kt < 1024; kt += 64) {
    #pragma unroll
    for (int is = 0; is < 4; ++is) {
      int slot = is*256 + tid;
      int r = slot >> 3;
      int cs = (slot & 7) ^ (r & 7);
      gload_lds16(A  + (m0  + r)*1024 + kt + cs*8, As + (is*256 + wave*64)*8);
      gload_lds16(Bm + (nloc+ r)*1024 + kt + cs*8, Bs + (is*256 + wave*64)*8);
    }
    __syncthreads();
    #pragma unroll
    for (int kk = 0; kk < 2; ++kk) {
      bf16x8 av[4], bv[4];
      #pragma unroll
      for (int m = 0; m < 4; ++m) {
        int r = wr + m*16 + lr;
        av[m] = *(const bf16x8*)(As + (r*8 + ((kk*4 + lk) ^ (r & 7)))*8);
      }
      #pragma unroll
      for (int n = 0; n < 4; ++n) {
        int r = wc + n*16 + lr;
        bv[n] = *(const bf16x8*)(Bs + (r*8 + ((kk*4 + lk) ^ (r & 7)))*8);
      }
      #pragma unroll
      for (int m = 0; m < 4; ++m)
        #pragma unroll
        for (int n = 0; n < 4; ++n)
          acc[m][n] = __builtin_amdgcn_mfma_f32_16x16x32_bf16(av[m], bv[n], acc[m][n], 0, 0, 0);
    }
    __syncthreads();
  }

  // Epilogue. C/D frag: col = lane&15, row = (lane>>4)*4 + j  [m89].
  if (MODE == 0) {
    if (proj < 2) {
      // Q,K -> [B,H,S,64]
      short* outp = proj == 0 ? o0 : o1;
      const float scale = (proj == 0) ? 0.125f : 1.0f;
      #pragma unroll
      for (int n = 0; n < 4; ++n) {
        int col = nloc + wc + n*16 + lr;
        int h = col >> 6, d = col & 63;
        float bvv = bias[col];
        #pragma unroll
        for (int m = 0; m < 4; ++m)
          #pragma unroll
          for (int j = 0; j < 4; ++j) {
            int row = m0 + wr + m*16 + lk*4 + j;
            int b = row >> 11, s = row & 2047;
            outp[(((b*NH + h)*SEQ + s) << 6) + d] = f2bf((acc[m][n][j] + bvv) * scale);
          }
      }
    } else {
      // V -> transposed [B,H,64,S]; j is contiguous in s -> packed 8B stores
      #pragma unroll
      for (int n = 0; n < 4; ++n) {
        int col = nloc + wc + n*16 + lr;
        int h = col >> 6, d = col & 63;
        float bvv = bias[col];
        #pragma unroll
        for (int m = 0; m < 4; ++m) {
          int row = m0 + wr + m*16 + lk*4;   // j=0; s0..s0+3 contiguous
          int b = row >> 11, s = row & 2047;
          short4 vv;
          vv.x = f2bf(acc[m][n][0] + bvv);
          vv.y = f2bf(acc[m][n][1] + bvv);
          vv.z = f2bf(acc[m][n][2] + bvv);
          vv.w = f2bf(acc[m][n][3] + bvv);
          *(short4*)(o2 + (((b*NH + h)*64 + d)*SEQ + s)) = vv;
        }
      }
    }
  } else {
    #pragma unroll
    for (int n = 0; n < 4; ++n) {
      int col = n0 + wc + n*16 + lr;
      float bvv = bias[col];
      #pragma unroll
      for (int m = 0; m < 4; ++m)
        #pragma unroll
        for (int j = 0; j < 4; ++j) {
          int row = m0 + wr + m*16 + lk*4 + j;
          of[row*HID + col] = acc[m][n][j] + bvv;
        }
    }
  }
}

// Flash attention. Q,K: [B,H,S,64] bf16 (Q pre-scaled 0.125). VT: [B,H,64,S] bf16.
// O: [B,S,H*64] bf16. Block = (b,h, 64 q-rows); wave w owns 16 q-rows. KV tiles of 64.
__global__ __launch_bounds__(256, 2)
void attn_fwd(const short* __restrict__ Q, const short* __restrict__ K,
              const short* __restrict__ VT, const float* __restrict__ head_mask,
              short* __restrict__ O) {
  __shared__ __align__(16) short Ks[64*64];      // [kv][d], swizzled f=r&7
  __shared__ __align__(16) short Vs[64*64];      // [d][kv], swizzled f=r&7 (staged from VT)
  __shared__ __align__(16) short Ps[4][16*64];   // per-wave P [q][kv], swizzled f=row>>1
  const int tid = threadIdx.x;
  const int wave = tid >> 6, lane = tid & 63;
  const int lr = lane & 15, lk = lane >> 4;
  const int bh = blockIdx.y;
  const int h = bh & (NH - 1);
  const int q0 = blockIdx.x * 64;
  const short* Qh = Q  + bh * SEQ * 64;
  const short* Kh = K  + bh * SEQ * 64;
  const short* Vh = VT + bh * 64 * SEQ;

  // Q A-fragments: row = lane&15, k = (lane>>4)*8 + j
  bf16x8 qf[2];
  {
    const short* qr = Qh + (q0 + wave*16 + lr)*64 + lk*8;
    qf[0] = *(const bf16x8*)qr;
    qf[1] = *(const bf16x8*)(qr + 32);
  }

  float row_m[4], row_l[4];
  f32x4 oacc[4];
  #pragma unroll
  for (int j = 0; j < 4; ++j) { row_m[j] = -1e30f; row_l[j] = 0.f; }
  #pragma unroll
  for (int n = 0; n < 4; ++n) oacc[n] = (f32x4){0.f,0.f,0.f,0.f};

  for (int kv0 = 0; kv0 < SEQ; kv0 += 64) {
    // Stage K tile [kv 64][d 64] and V^T tile [d 64][kv 64] (both pre-swizzled source)
    #pragma unroll
    for (int is = 0; is < 2; ++is) {
      int slot = is*256 + tid;
      int r = slot >> 3;
      int cs = (slot & 7) ^ (r & 7);
      gload_lds16(Kh + (kv0 + r)*64 + cs*8, Ks + (is*256 + wave*64)*8);
      gload_lds16(Vh + r*SEQ + kv0 + cs*8, Vs + (is*256 + wave*64)*8);
    }
    __syncthreads();

    // S = Q @ K^T : frag n covers kv cols [n*16, +16)
    f32x4 sc[4];
    #pragma unroll
    for (int n = 0; n < 4; ++n) sc[n] = (f32x4){0.f,0.f,0.f,0.f};
    #pragma unroll
    for (int kk = 0; kk < 2; ++kk)
      #pragma unroll
      for (int n = 0; n < 4; ++n) {
        int r = n*16 + lr;
        bf16x8 bv = *(const bf16x8*)(Ks + (r*8 + ((kk*4 + lk) ^ (r & 7)))*8);
        sc[n] = __builtin_amdgcn_mfma_f32_16x16x32_bf16(qf[kk], bv, sc[n], 0, 0, 0);
      }

    // Online softmax. q-row = lk*4+j, lanes [lk*16, +16), reg j.
    float pmax[4];
    #pragma unroll
    for (int j = 0; j < 4; ++j) {
      float v = fmaxf(fmaxf(sc[0][j], sc[1][j]), fmaxf(sc[2][j], sc[3][j]));
      v = fmaxf(v, __shfl_xor(v, 1));
      v = fmaxf(v, __shfl_xor(v, 2));
      v = fmaxf(v, __shfl_xor(v, 4));
      v = fmaxf(v, __shfl_xor(v, 8));
      pmax[j] = v;
    }
    float ps[4], rs[4];
    #pragma unroll
    for (int j = 0; j < 4; ++j) {
      float mn = fmaxf(row_m[j], pmax[j]);
      ps[j] = __expf(row_m[j] - mn);
      row_m[j] = mn;
      rs[j] = 0.f;
    }
    #pragma unroll
    for (int n = 0; n < 4; ++n)
      #pragma unroll
      for (int j = 0; j < 4; ++j) {
        float p = __expf(sc[n][j] - row_m[j]);
        sc[n][j] = p;
        rs[j] += p;
      }
    #pragma unroll
    for (int j = 0; j < 4; ++j) {
      float v = rs[j];
      v += __shfl_xor(v, 1);
      v += __shfl_xor(v, 2);
      v += __shfl_xor(v, 4);
      v += __shfl_xor(v, 8);
      row_l[j] = row_l[j]*ps[j] + v;
    }
    #pragma unroll
    for (int n = 0; n < 4; ++n)
      #pragma unroll
      for (int j = 0; j < 4; ++j) oacc[n][j] *= ps[j];

    // P -> per-wave LDS (bf16), swizzle f(row)=row>>1 (write-conflict-free, reads 2-way)
    short* Pw = Ps[wave];
    #pragma unroll
    for (int n = 0; n < 4; ++n)
      #pragma unroll
      for (int j = 0; j < 4; ++j) {
        int row = lk*4 + j;
        int col = n*16 + lr;
        int byteoff = row*128 + (((col >> 3) ^ (row >> 1))*16) + (col & 7)*2;
        *(short*)((char*)Pw + byteoff) = f2bf(sc[n][j]);
      }
    __syncthreads();

    // O += P @ V ; frag n covers d cols [n*16, +16); B-frag from Vs like K
    #pragma unroll
    for (int kk = 0; kk < 2; ++kk) {
      bf16x8 av = *(const bf16x8*)(Pw + (lr*8 + ((kk*4 + lk) ^ (lr >> 1)))*8);
      #pragma unroll
      for (int n = 0; n < 4; ++n) {
        int r = n*16 + lr;
        bf16x8 bv = *(const bf16x8*)(Vs + (r*8 + ((kk*4 + lk) ^ (r & 7)))*8);
        oacc[n] = __builtin_amdgcn_mfma_f32_16x16x32_bf16(av, bv, oacc[n], 0, 0, 0);
      }
    }
    __syncthreads();
  }

  const float hm = head_mask[h];
  const int b = bh >> 4;
  #pragma unroll
  for (int j = 0; j < 4; ++j) {
    int q = q0 + wave*16 + lk*4 + j;
    float inv = hm / row_l[j];
    int rowbase = (b*SEQ + q)*HID + h*64;
    #pragma unroll
    for (int n = 0; n < 4; ++n)
      O[rowbase + n*16 + lr] = f2bf(oacc[n][j] * inv);
  }
}

extern "C" void kernel_launch(void* const* d_in, const int* in_sizes, int n_in,
                              void* d_out, int out_size, void* d_ws, size_t ws_size,
                              hipStream_t stream) {
  const float* x  = (const float*)d_in[0];
  const float* Wq = (const float*)d_in[1];
  const float* bq = (const float*)d_in[2];
  const float* Wk = (const float*)d_in[3];
  const float* bk = (const float*)d_in[4];
  const float* Wv = (const float*)d_in[5];
  const float* bv = (const float*)d_in[6];
  const float* Wo = (const float*)d_in[7];
  const float* bo = (const float*)d_in[8];
  const float* hm = (const float*)d_in[9];
  float* out = (float*)d_out;
  char* ws = (char*)d_ws;

  short* xb  = (short*)(ws);
  short* wqb = (short*)(ws + 16777216);
  short* wkb = (short*)(ws + 18874368);
  short* wvb = (short*)(ws + 20971520);
  short* wob = (short*)(ws + 23068672);
  short* Qb  = (short*)(ws + 25165824);
  short* Kb  = (short*)(ws + 41943040);
  short* Vb  = (short*)(ws + 58720256);   // holds V^T [B,H,64,S]
  short* AOb = (short*)(ws + 75497472);

  cvt_f32_bf16<<<8192, 256, 0, stream>>>((const float4*)x,  (short4*)xb,  2097152);
  cvt_f32_bf16<<<1024, 256, 0, stream>>>((const float4*)Wq, (short4*)wqb, 262144);
  cvt_f32_bf16<<<1024, 256, 0, stream>>>((const float4*)Wk, (short4*)wkb, 262144);
  cvt_f32_bf16<<<1024, 256, 0, stream>>>((const float4*)Wv, (short4*)wvb, 262144);
  cvt_f32_bf16<<<1024, 256, 0, stream>>>((const float4*)Wo, (short4*)wob, 262144);

  gemm_bf16<0><<<dim3(24, 64), 256, 0, stream>>>(xb, wqb, wkb, wvb, bq, bk, bv,
                                                 Qb, Kb, Vb, nullptr);
  attn_fwd<<<dim3(32, 64), 256, 0, stream>>>(Qb, Kb, Vb, hm, AOb);
  gemm_bf16<1><<<dim3(8, 64), 256, 0, stream>>>(AOb, wob, nullptr, nullptr, bo, nullptr, nullptr,
                                                nullptr, nullptr, nullptr, out);
}